// Round 16
// baseline (344.328 us; speedup 1.0000x reference)
//
#include <hip/hip_runtime.h>

// CapsNet dynamic routing — fp32 in / fp32 out.
// R15 lesson: passes are 84% stalled — global->LDS->barrier chain serialized
// per iteration. R16: (a) software-pipeline the W tile (prefetch iter+1 into
// registers during iter's compute), (b) pass 0 has no softmax -> drop the
// LDS tile and ALL per-iter barriers, direct W reads.
// B=64, Ni=1152, Di=8, No=64, Do=16.
// u[b,i,o,d] = sum_k W[i*8192 + (o*16+d)*8 + k] * x[b*9216 + i*8 + k]
// it0: c=1/64       -> s0 -> v0
// it1: l=<u,v0>     -> c1 -> s1 -> v1
// it2: l=<u,v0+v1>  -> c2 (OUT [B,Ni,No]) -> s2 -> v2 (OUT [B,No,Do])

#define B_      64
#define NI_     1152
#define DI_     8
#define NO_     64
#define DO_     16
#define NOD_    1024
#define CH_     96
#define CI_     12
#define BG_     8
#define BSPLIT_ 8
#define V_ELEMS 65536
#define PADR    33      // float4 slots per o-row in LDS tile (132 floats)

static_assert(CH_ * CI_ == NI_, "chunking");
static_assert(BG_ * BSPLIT_ == B_, "b split");

// ---------------- pass 0: no softmax -> barrier-free W streaming ----------------
__global__ __launch_bounds__(256, 4)
void caps_pass0(const float* __restrict__ X,
                const float* __restrict__ W,
                float* __restrict__ part)
{
    __shared__ float x_lds[BG_][CI_ * DI_];   // 3 KB only

    const int t  = threadIdx.x;
    const int ch = blockIdx.x;
    const int b0 = blockIdx.y * BG_;
    const int i0 = ch * CI_;

    for (int f = t; f < BG_ * CI_ * DI_ / 4; f += 256) {
        int bb = f / (CI_ * DI_ / 4), r = f - bb * (CI_ * DI_ / 4);
        ((float4*)x_lds)[f] =
            ((const float4*)(X + ((size_t)(b0 + bb) * NI_ + i0) * DI_))[r];
    }
    __syncthreads();   // the only barrier

    float acc[BG_][4];
#pragma unroll
    for (int b = 0; b < BG_; ++b) { acc[b][0]=0.f; acc[b][1]=0.f; acc[b][2]=0.f; acc[b][3]=0.f; }

    const float4* Wq = (const float4*)W;

    for (int ci = 0; ci < CI_; ++ci) {
        const int i = i0 + ci;
        // thread t owns W[i] floats [t*32, t*32+32): 8 dwordx4 (L1 reuses lines)
        const float4* wp = Wq + (size_t)i * 2048 + (size_t)t * 8;
        float wf[4][8];
#pragma unroll
        for (int j = 0; j < 4; ++j) {
            float4 q0 = wp[2*j], q1 = wp[2*j + 1];
            wf[j][0]=q0.x; wf[j][1]=q0.y; wf[j][2]=q0.z; wf[j][3]=q0.w;
            wf[j][4]=q1.x; wf[j][5]=q1.y; wf[j][6]=q1.z; wf[j][7]=q1.w;
        }
#pragma unroll
        for (int b = 0; b < BG_; ++b) {
            const float* xb = &x_lds[b][ci * DI_];
            const float x0=xb[0],x1=xb[1],x2=xb[2],x3=xb[3];
            const float x4=xb[4],x5=xb[5],x6=xb[6],x7=xb[7];
#pragma unroll
            for (int j = 0; j < 4; ++j) {
                float s = wf[j][0] * x0;
                s = fmaf(wf[j][1], x1, s); s = fmaf(wf[j][2], x2, s);
                s = fmaf(wf[j][3], x3, s); s = fmaf(wf[j][4], x4, s);
                s = fmaf(wf[j][5], x5, s); s = fmaf(wf[j][6], x6, s);
                s = fmaf(wf[j][7], x7, s);
                acc[b][j] += s;
            }
        }
    }

#pragma unroll
    for (int b = 0; b < BG_; ++b) {
        float4 val;
        val.x=acc[b][0]; val.y=acc[b][1]; val.z=acc[b][2]; val.w=acc[b][3];
        *((float4*)(part + (((size_t)(b0 + b) * CH_ + ch) * NOD_ + 4 * t))) = val;
    }
}

// ---------------- passes 1/2: LDS tile + register prefetch pipeline ----------------
// MODE 1: l=<u,v0>, softmax over o, acc c*u             -> part
// MODE 2: l=<u,v0+v1>, softmax, write c (fp32), acc c*u -> part
template <int MODE>
__global__ __launch_bounds__(256, 3)
void caps_pass(const float* __restrict__ X,
               const float* __restrict__ W,
               const float* __restrict__ vin,
               float* __restrict__ part,
               float* __restrict__ rw)
{
    __shared__ float  x_lds[BG_][CI_ * DI_];   // 3 KB
    __shared__ float4 wtile[NO_ * PADR];       // 33 KB padded W tile
    __shared__ float  e_lds[BG_][NO_];         // 2 KB
    __shared__ float  invS[BG_];

    const int t  = threadIdx.x;
    const int o  = t >> 2, q = t & 3;
    const int ch = blockIdx.x;
    const int b0 = blockIdx.y * BG_;
    const int i0 = ch * CI_;

    for (int f = t; f < BG_ * CI_ * DI_ / 4; f += 256) {
        int bb = f / (CI_ * DI_ / 4), r = f - bb * (CI_ * DI_ / 4);
        ((float4*)x_lds)[f] =
            ((const float4*)(X + ((size_t)(b0 + bb) * NI_ + i0) * DI_))[r];
    }
    float vreg[BG_][4];
#pragma unroll
    for (int b = 0; b < BG_; ++b) {
        float4 qv = *((const float4*)(vin + (size_t)(b0 + b) * NOD_ + 4 * t));
        vreg[b][0]=qv.x; vreg[b][1]=qv.y; vreg[b][2]=qv.z; vreg[b][3]=qv.w;
    }

    float acc[BG_][4];
#pragma unroll
    for (int b = 0; b < BG_; ++b) { acc[b][0]=0.f; acc[b][1]=0.f; acc[b][2]=0.f; acc[b][3]=0.f; }

    const float4* Wq = (const float4*)W;

    // prefetch tile 0 into registers
    float4 tmp[8];
    {
        const float4* wg = Wq + (size_t)i0 * 2048;
#pragma unroll
        for (int j = 0; j < 8; ++j) tmp[j] = wg[t + 256 * j];
    }
    __syncthreads();   // x_lds ready (overlapped with tile-0 loads)

    for (int ci = 0; ci < CI_; ++ci) {
        const int i = i0 + ci;

        // commit prefetched tile to LDS.
        // WAR safety: iter ci-1's tile reads precede its barrier B/C, which
        // every thread passed before reaching this write.
#pragma unroll
        for (int j = 0; j < 8; ++j) {
            const int f = t + 256 * j;
            wtile[(f >> 5) * PADR + (f & 31)] = tmp[j];
        }
        __syncthreads();   // A: tile ready

        // read my fragment
        float wf[4][8];
#pragma unroll
        for (int jj = 0; jj < 4; ++jj) {
            float4 a0 = wtile[o * PADR + (4 * q + jj) * 2];
            float4 a1 = wtile[o * PADR + (4 * q + jj) * 2 + 1];
            wf[jj][0]=a0.x; wf[jj][1]=a0.y; wf[jj][2]=a0.z; wf[jj][3]=a0.w;
            wf[jj][4]=a1.x; wf[jj][5]=a1.y; wf[jj][6]=a1.z; wf[jj][7]=a1.w;
        }

        // issue next tile's loads NOW — latency hides behind compute+B+C
        if (ci + 1 < CI_) {
            const float4* wg = Wq + (size_t)(i + 1) * 2048;
#pragma unroll
            for (int j = 0; j < 8; ++j) tmp[j] = wg[t + 256 * j];
        }

        float u[BG_][4];
#pragma unroll
        for (int b = 0; b < BG_; ++b) {
            const float* xb = &x_lds[b][ci * DI_];
            const float x0=xb[0],x1=xb[1],x2=xb[2],x3=xb[3];
            const float x4=xb[4],x5=xb[5],x6=xb[6],x7=xb[7];
#pragma unroll
            for (int jj = 0; jj < 4; ++jj) {
                float s = wf[jj][0] * x0;
                s = fmaf(wf[jj][1], x1, s); s = fmaf(wf[jj][2], x2, s);
                s = fmaf(wf[jj][3], x3, s); s = fmaf(wf[jj][4], x4, s);
                s = fmaf(wf[jj][5], x5, s); s = fmaf(wf[jj][6], x6, s);
                s = fmaf(wf[jj][7], x7, s);
                u[b][jj] = s;
            }
            float a = u[b][0]*vreg[b][0] + u[b][1]*vreg[b][1]
                    + u[b][2]*vreg[b][2] + u[b][3]*vreg[b][3];
            a += __shfl_xor(a, 1);
            a += __shfl_xor(a, 2);          // full 16-d dot within quad
            if (q == 0) e_lds[b][o] = __expf(a);
        }

        __syncthreads();   // B: e_lds complete (fences tile reads too)
        {
            const int bb = t >> 5, l = t & 31;
            float s = e_lds[bb][l] + e_lds[bb][l + 32];
            s += __shfl_xor(s, 1);  s += __shfl_xor(s, 2);  s += __shfl_xor(s, 4);
            s += __shfl_xor(s, 8);  s += __shfl_xor(s, 16);
            if (l == 0) invS[bb] = 1.0f / s;
        }
        __syncthreads();   // C: invS ready
#pragma unroll
        for (int b = 0; b < BG_; ++b) {
            const float c = e_lds[b][o] * invS[b];
            acc[b][0] = fmaf(c, u[b][0], acc[b][0]);
            acc[b][1] = fmaf(c, u[b][1], acc[b][1]);
            acc[b][2] = fmaf(c, u[b][2], acc[b][2]);
            acc[b][3] = fmaf(c, u[b][3], acc[b][3]);
            if (MODE == 2 && q == 0)
                rw[((size_t)(b0 + b) * NI_ + i) * NO_ + o] = c;
        }
    }

#pragma unroll
    for (int b = 0; b < BG_; ++b) {
        float4 val;
        val.x=acc[b][0]; val.y=acc[b][1]; val.z=acc[b][2]; val.w=acc[b][3];
        *((float4*)(part + (((size_t)(b0 + b) * CH_ + ch) * NOD_ + 4 * t))) = val;
    }
}

// Reduce partials over CH_ chunks (float4), squash over d, emit v.
template <int MODE>
__global__ __launch_bounds__(128)
void caps_squash(const float* __restrict__ part, const float* __restrict__ v0in,
                 float* __restrict__ vout)
{
    const int c4 = blockIdx.x * 128 + threadIdx.x;    // b*256 + o*4 + dq
    const int b = c4 >> 8, od4 = c4 & 255;
    const float4* p = (const float4*)part + (size_t)b * CH_ * 256 + od4;
    float4 s = {0.f, 0.f, 0.f, 0.f};
#pragma unroll 8
    for (int ch = 0; ch < CH_; ++ch) {
        float4 q = p[(size_t)ch * 256];
        s.x += q.x; s.y += q.y; s.z += q.z; s.w += q.w;
    }
    if (MODE == 0) { s.x*=(1.f/64.f); s.y*=(1.f/64.f); s.z*=(1.f/64.f); s.w*=(1.f/64.f); }
    float s2 = s.x*s.x + s.y*s.y + s.z*s.z + s.w*s.w;
    s2 += __shfl_xor(s2, 1); s2 += __shfl_xor(s2, 2);   // 4 dq-lanes = 16 d
    const float scale = s2 / ((1.0f + s2) * sqrtf(s2 + 1e-7f));
    float4 v; v.x = scale*s.x; v.y = scale*s.y; v.z = scale*s.z; v.w = scale*s.w;
    if (MODE == 1) {
        float4 v0 = ((const float4*)v0in)[c4];
        v.x += v0.x; v.y += v0.y; v.z += v0.z; v.w += v0.w;
    }
    ((float4*)vout)[c4] = v;
}

// Safety fallback (R11's passing kernel) — only if ws is unexpectedly tiny.
__global__ __launch_bounds__(1024, 1)
void caps_naive(const float* __restrict__ X, const float* __restrict__ W,
                float* __restrict__ outv, float* __restrict__ outc)
{
    __shared__ float xs[NI_ * DI_];
    __shared__ float agree[NO_];
    __shared__ float expo[NO_];
    __shared__ float s2sh[NO_];
    __shared__ float den;

    const int b = blockIdx.x, tid = threadIdx.x;
    const int o = tid >> 4, d = tid & 15;

    for (int f = tid; f < NI_ * DI_; f += 1024)
        xs[f] = X[(size_t)b * NI_ * DI_ + f];
    __syncthreads();

    float vprev = 0.f, v0 = 0.f, vout = 0.f;
    for (int phase = 0; phase < 3; ++phase) {
        float sacc = 0.f;
        for (int i = 0; i < NI_; ++i) {
            const float* wp = W + (size_t)i * 8192 + (size_t)tid * 8;
            const float* xp = xs + i * DI_;
            float u = 0.f;
#pragma unroll
            for (int k = 0; k < 8; ++k) u = fmaf(wp[k], xp[k], u);
            if (phase == 0) { sacc += u; continue; }
            if (d == 0) agree[o] = 0.f;
            __syncthreads();
            atomicAdd(&agree[o], u * vprev);
            __syncthreads();
            if (tid == 0) den = 0.f;
            __syncthreads();
            if (d == 0) { float e = __expf(agree[o]); expo[o] = e; atomicAdd(&den, e); }
            __syncthreads();
            float c = expo[o] / den;
            sacc = fmaf(c, u, sacc);
            if (phase == 2 && d == 0)
                outc[((size_t)b * NI_ + i) * NO_ + o] = c;
            __syncthreads();
        }
        if (phase == 0) sacc *= (1.0f / 64.0f);
        if (d == 0) s2sh[o] = 0.f;
        __syncthreads();
        atomicAdd(&s2sh[o], sacc * sacc);
        __syncthreads();
        const float s2 = s2sh[o];
        const float scale = s2 / ((1.0f + s2) * sqrtf(s2 + 1e-7f));
        const float vv = scale * sacc;
        if (phase == 0)      { v0 = vv; vprev = vv; }
        else if (phase == 1) { vprev = v0 + vv; }
        else                 { vout = vv; }
        __syncthreads();
    }
    outv[(size_t)b * (NO_ * DO_) + tid] = vout;
}

extern "C" void kernel_launch(void* const* d_in, const int* in_sizes, int n_in,
                              void* d_out, int out_size, void* d_ws, size_t ws_size,
                              hipStream_t stream)
{
    const float *X, *W;
    if (in_sizes[0] < in_sizes[1]) { X = (const float*)d_in[0]; W = (const float*)d_in[1]; }
    else                           { X = (const float*)d_in[1]; W = (const float*)d_in[0]; }

    float* out  = (float*)d_out;
    float* outv = out;             // v: [B,No,Do] fp32
    float* outc = out + V_ELEMS;   // c: [B,Ni,No] fp32

    const size_t needBig = ((size_t)B_ * CH_ * NOD_ + 2 * (size_t)B_ * NOD_) * sizeof(float);
    if (ws_size < needBig) {       // never expected (ws >= 64 MB measured R12)
        caps_naive<<<B_, 1024, 0, stream>>>(X, W, outv, outc);
        return;
    }

    float* part = (float*)d_ws;                      // 25.2 MB
    float* v0   = part + (size_t)B_ * CH_ * NOD_;
    float* w01  = v0 + (size_t)B_ * NOD_;

    dim3 gP(CH_, BSPLIT_), blk(256), gS(128), blkS(128);
    caps_pass0<<<gP, blk, 0, stream>>>(X, W, part);
    caps_squash<0><<<gS, blkS, 0, stream>>>(part, nullptr, v0);
    caps_pass<1><<<gP, blk, 0, stream>>>(X, W, v0, part, nullptr);
    caps_squash<1><<<gS, blkS, 0, stream>>>(part, v0, w01);
    caps_pass<2><<<gP, blk, 0, stream>>>(X, W, w01, part, outc);
    caps_squash<2><<<gS, blkS, 0, stream>>>(part, nullptr, outv);
}